// Round 8
// baseline (413.950 us; speedup 1.0000x reference)
//
#include <hip/hip_runtime.h>

// Sizes fixed by the problem.
#define TT 1653          // T
#define DD 512           // D
#define BB 2             // B
#define DE 64            // D/E
#define BEH 16           // B*E
#define TTILES 26        // ceil(T/64)
#define TPAD 1664        // T padded to multiple of 64
#define SQN 26           // ovt s-tiles (TPAD/64)
#define NJC 4            // ovt j-split
#define MPSTRIDE TPAD    // Mpart row stride (floats)

typedef __attribute__((ext_vector_type(8))) short bf16x8;   // 8 bf16 (4 VGPRs)
typedef __attribute__((ext_vector_type(4))) float f32x4;
typedef short bf16x8u __attribute__((ext_vector_type(8), aligned(4)));
typedef float f32x4u  __attribute__((ext_vector_type(4), aligned(4)));  // O rows only 4B-aligned (TT odd)

__device__ __forceinline__ short f2bf(float f) {
    union { float f; unsigned u; } v; v.f = f;
    unsigned r = v.u + 0x7fffu + ((v.u >> 16) & 1u);   // RNE
    return (short)(r >> 16);
}
__device__ __forceinline__ unsigned pack2(float a, float b) {
    return (unsigned)(unsigned short)f2bf(a) | ((unsigned)(unsigned short)f2bf(b) << 16);
}
__device__ __forceinline__ float bf2f(short s) {
    union { unsigned u; float f; } v; v.u = ((unsigned)(unsigned short)s) << 16;
    return v.f;
}
__device__ __forceinline__ bf16x8 ld_frag4(const short* p) {   // 4B-aligned LDS frag load
    bf16x8u v = *(const bf16x8u*)p;
    return (bf16x8)v;
}

// Raw barriers (no vmcnt drain); compiler emits counted vmcnt at reg uses.
__device__ __forceinline__ void bar_fenced() {
    __builtin_amdgcn_sched_barrier(0);
    __builtin_amdgcn_s_barrier();
    __builtin_amdgcn_sched_barrier(0);
}
__device__ __forceinline__ void lgkm0_bar() {
    asm volatile("s_waitcnt lgkmcnt(0)" ::: "memory");
    __builtin_amdgcn_sched_barrier(0);
    __builtin_amdgcn_s_barrier();
    __builtin_amdgcn_sched_barrier(0);
}

// ---------------------------------------------------------------------------
// Kernel 0 (prep): one memory-bound pass that converts
//   X fp32 -> bf16, Wq/Wk/Wv fp32 -> bf16, punish fp32 -> Pbf bf16 [T][TPAD].
// ---------------------------------------------------------------------------
__global__ __launch_bounds__(256) void prep_kernel(
    const float* __restrict__ X,
    const float* __restrict__ Wq, const float* __restrict__ Wk,
    const float* __restrict__ Wv, const float* __restrict__ P,
    short* __restrict__ Xb16,
    short* __restrict__ Wqb, short* __restrict__ Wkb, short* __restrict__ Wvb,
    short* __restrict__ Pbf)
{
    const int NX4 = (BB * TT * DD) / 4;       // 423168
    const int NW4 = (DD * DD) / 4;            // 65536
    const int NP4 = TT * (TPAD / 4);          // 687648
    const int total = NX4 + 3 * NW4 + NP4;
    const int stride = gridDim.x * 256;

    for (int g = blockIdx.x * 256 + threadIdx.x; g < total; g += stride) {
        if (g < NX4 + 3 * NW4) {
            const float* src; short* dst; int idx4;
            if (g < NX4)                { src = X;  dst = Xb16; idx4 = g; }
            else if (g < NX4 + NW4)     { src = Wq; dst = Wqb;  idx4 = g - NX4; }
            else if (g < NX4 + 2 * NW4) { src = Wk; dst = Wkb;  idx4 = g - NX4 - NW4; }
            else                        { src = Wv; dst = Wvb;  idx4 = g - NX4 - 2 * NW4; }
            float4 a = *(const float4*)(src + (size_t)idx4 * 4);
            uint2 o; o.x = pack2(a.x, a.y); o.y = pack2(a.z, a.w);
            *(uint2*)(dst + (size_t)idx4 * 4) = o;
        } else {
            const int gp = g - (NX4 + 3 * NW4);
            const int r = gp / (TPAD / 4), c4 = (gp - r * (TPAD / 4)) * 4;
            float p0 = 0.f, p1 = 0.f, p2 = 0.f, p3 = 0.f;
            const float* prow = P + (size_t)r * TT;
            if (c4 + 0 < TT) p0 = prow[c4 + 0];
            if (c4 + 1 < TT) p1 = prow[c4 + 1];
            if (c4 + 2 < TT) p2 = prow[c4 + 2];
            if (c4 + 3 < TT) p3 = prow[c4 + 3];
            uint2 o; o.x = pack2(p0, p1); o.y = pack2(p2, p3);
            *(uint2*)(Pbf + (size_t)r * TPAD + c4) = o;
        }
    }
}

// ---------------------------------------------------------------------------
// Kernel 1 (MFMA): projections from pre-converted bf16 inputs (unchanged R7).
// ---------------------------------------------------------------------------
__global__ __launch_bounds__(256) void proj7_kernel(
    const short* __restrict__ Xb16,
    const short* __restrict__ W0b, const float* __restrict__ b0,
    const short* __restrict__ W1b, const float* __restrict__ b1,
    const short* __restrict__ W2b, const float* __restrict__ b2,
    short* __restrict__ Y0, short* __restrict__ Y1, short* __restrict__ Y2)
{
    __shared__ __align__(16) short Wsh[64][72];  // [d][k] bf16
    __shared__ __align__(16) short Xs[64][72];   // [t][k] bf16

    const int tt = blockIdx.x, dt = blockIdx.y, z = blockIdx.z;
    const int b = z / 3, which = z % 3;
    const short* W    = (which == 0) ? W0b : (which == 1) ? W1b : W2b;
    const float* bias = (which == 0) ? b0 : (which == 1) ? b1 : b2;
    short* Y          = (which == 0) ? Y0 : (which == 1) ? Y1 : Y2;

    const int t0 = tt * 64, d0 = dt * 64;
    const short* Xb = Xb16 + (size_t)b * TT * DD;

    const int tid  = threadIdx.x;
    const int wave = tid >> 6, lane = tid & 63;
    const int quad = lane >> 4, l16 = lane & 15;
    const int srow = tid >> 2, scg = (tid & 3) * 16;
    const int trow = t0 + srow;
    const int rx = min(trow, TT - 1);

    f32x4 acc[4];
    #pragma unroll
    for (int i = 0; i < 4; ++i) acc[i] = (f32x4){0.f, 0.f, 0.f, 0.f};

    uint4 wlo, whi, xlo, xhi;

    auto stage = [&](int k0) {   // raw bf16 tile loads
        const short* wrow = W + (size_t)(d0 + srow) * DD + k0 + scg;
        wlo = *(const uint4*)(wrow);
        whi = *(const uint4*)(wrow + 8);
        const short* xrow = Xb + (size_t)rx * DD + k0 + scg;
        xlo = *(const uint4*)(xrow);
        xhi = *(const uint4*)(xrow + 8);
    };
    auto lds_write = [&]() {
        const uint4 z4 = make_uint4(0u, 0u, 0u, 0u);
        const bool tv = (trow < TT);
        uint4 y0 = tv ? xlo : z4, y1 = tv ? xhi : z4;
        *(uint4*)&Wsh[srow][scg]     = wlo;
        *(uint4*)&Wsh[srow][scg + 8] = whi;
        *(uint4*)&Xs[srow][scg]      = y0;
        *(uint4*)&Xs[srow][scg + 8]  = y1;
    };

    stage(0);
    for (int k0 = 0; k0 < DD; k0 += 64) {
        lds_write();
        if (k0 + 64 < DD) stage(k0 + 64);   // stays in flight across barriers
        lgkm0_bar();

        #pragma unroll
        for (int ks = 0; ks < 2; ++ks) {
            bf16x8 a = *(const bf16x8*)&Wsh[wave * 16 + l16][ks * 32 + quad * 8];
            #pragma unroll
            for (int nt = 0; nt < 4; ++nt) {
                bf16x8 bb = *(const bf16x8*)&Xs[nt * 16 + l16][ks * 32 + quad * 8];
                acc[nt] = __builtin_amdgcn_mfma_f32_16x16x32_bf16(a, bb, acc[nt], 0, 0, 0);
            }
        }
        bar_fenced();
    }

    #pragma unroll
    for (int nt = 0; nt < 4; ++nt) {
        const int t = t0 + nt * 16 + l16;
        if (t < TT) {
            #pragma unroll
            for (int r = 0; r < 4; ++r) {
                const int d = d0 + wave * 16 + quad * 4 + r;
                float v = acc[nt][r] + bias[d];
                if (which < 2) v = 1.2f / (1.0f + __expf(-1.6f * v));
                Y[((size_t)b * DD + d) * TT + t] = f2bf(v);
            }
        }
    }
}

// ---------------------------------------------------------------------------
// Kernel 2 (MFMA): partial Mt. v8 (unchanged R7): XCD-colocated,
// 256B-contiguous O reads, stride-70 LDS, raw counted barriers.
//   Mpart[jc][be][d][s] = sum_{j in chunk jc} V[j][d] * O[j][s]
// ---------------------------------------------------------------------------
struct OVStage {
    f32x4u o0a, o0b, o1a, o1b;    // O rows j0+2p, +1, +32, +33 ; cols 4sc..+3
    uint2  v0a, v0b, v1a, v1b;    // V same rows (raw, clamped)
};

__global__ __launch_bounds__(256) void ovt8_kernel(
    const float* __restrict__ orth, const short* __restrict__ Vb,
    float* __restrict__ Mpart)
{
    __shared__ __align__(16) short Os[64][70];  // [s_local][j_local] bf16
    __shared__ __align__(16) short Vs[64][70];  // [d][j_local] bf16

    // XCD-aware bijective remap of (sq, be, jc).
    const int flat = blockIdx.x + TTILES * (blockIdx.y + BEH * blockIdx.z);
    const int xcd = flat & 7;
    const int j8  = flat >> 3;            // 0..207
    const int sq  = j8 % 26;
    const int slice = xcd * 8 + (j8 / 26);  // 0..63
    const int be = slice & 15;
    const int jc = slice >> 4;            // 0..3

    const int s0 = sq * 64;
    const int jt0 = (jc < 2) ? jc * 7 : 14 + (jc - 2) * 6;   // tiles {7,7,6,6}
    const int jtn = (jc < 2) ? 7 : 6;

    const float* O  = orth + (size_t)be * TT * TT;
    const short* Vh = Vb + (size_t)be * DE * TT;

    const int tid  = threadIdx.x;
    const int wave = tid >> 6, lane = tid & 63;
    const int quad = lane >> 4, l16 = lane & 15;

    const int p  = tid >> 4;          // j-pair index (pairs p and p+16)
    const int sc = tid & 15;          // col group: local cols 4sc..4sc+3
    const int ca = s0 + 4 * sc;       // global col base
    const bool fastS = (s0 + 64 <= TT);

    f32x4 acc[4];
    #pragma unroll
    for (int i = 0; i < 4; ++i) acc[i] = (f32x4){0.f, 0.f, 0.f, 0.f};

    auto stage_load = [&](OVStage& S, int j0) {   // raw loads only
        const int jA = j0 + 2 * p;
        const int r0  = min(jA,      TT - 1);
        const int r0b = min(jA + 1,  TT - 1);
        const int r1  = min(jA + 32, TT - 1);
        const int r1b = min(jA + 33, TT - 1);
        if (fastS) {
            S.o0a = *(const f32x4u*)(O + (size_t)r0  * TT + ca);
            S.o0b = *(const f32x4u*)(O + (size_t)r0b * TT + ca);
            S.o1a = *(const f32x4u*)(O + (size_t)r1  * TT + ca);
            S.o1b = *(const f32x4u*)(O + (size_t)r1b * TT + ca);
        } else {
            #pragma unroll
            for (int i = 0; i < 4; ++i) {
                const int col = ca + i;
                const bool cv = (col < TT);
                S.o0a[i] = cv ? O[(size_t)r0  * TT + col] : 0.f;
                S.o0b[i] = cv ? O[(size_t)r0b * TT + col] : 0.f;
                S.o1a[i] = cv ? O[(size_t)r1  * TT + col] : 0.f;
                S.o1b[i] = cv ? O[(size_t)r1b * TT + col] : 0.f;
            }
        }
        S.v0a = *(const uint2*)(Vh + (size_t)r0  * DE + 4 * sc);
        S.v0b = *(const uint2*)(Vh + (size_t)r0b * DE + 4 * sc);
        S.v1a = *(const uint2*)(Vh + (size_t)r1  * DE + 4 * sc);
        S.v1b = *(const uint2*)(Vh + (size_t)r1b * DE + 4 * sc);
    };

    auto lds_write = [&](const OVStage& S, int j0) {
        const int jA = j0 + 2 * p;
        #pragma unroll
        for (int i = 0; i < 4; ++i) {
            *(unsigned*)&Os[4 * sc + i][2 * p]      = pack2(S.o0a[i], S.o0b[i]);
            *(unsigned*)&Os[4 * sc + i][2 * p + 32] = pack2(S.o1a[i], S.o1b[i]);
        }
        const uint2 z = make_uint2(0u, 0u);
        uint2 v0a = (jA      < TT) ? S.v0a : z;
        uint2 v0b = (jA + 1  < TT) ? S.v0b : z;
        uint2 v1a = (jA + 32 < TT) ? S.v1a : z;
        uint2 v1b = (jA + 33 < TT) ? S.v1b : z;
        *(unsigned*)&Vs[4 * sc + 0][2 * p]      = (v0a.x & 0xffffu) | (v0b.x << 16);
        *(unsigned*)&Vs[4 * sc + 1][2 * p]      = (v0a.x >> 16)     | (v0b.x & 0xffff0000u);
        *(unsigned*)&Vs[4 * sc + 2][2 * p]      = (v0a.y & 0xffffu) | (v0b.y << 16);
        *(unsigned*)&Vs[4 * sc + 3][2 * p]      = (v0a.y >> 16)     | (v0b.y & 0xffff0000u);
        *(unsigned*)&Vs[4 * sc + 0][2 * p + 32] = (v1a.x & 0xffffu) | (v1b.x << 16);
        *(unsigned*)&Vs[4 * sc + 1][2 * p + 32] = (v1a.x >> 16)     | (v1b.x & 0xffff0000u);
        *(unsigned*)&Vs[4 * sc + 2][2 * p + 32] = (v1a.y & 0xffffu) | (v1b.y << 16);
        *(unsigned*)&Vs[4 * sc + 3][2 * p + 32] = (v1a.y >> 16)     | (v1b.y & 0xffff0000u);
    };

    auto mfma_tile = [&]() {
        #pragma unroll
        for (int ks = 0; ks < 2; ++ks) {
            bf16x8 bb = ld_frag4(&Os[wave * 16 + l16][ks * 32 + quad * 8]);
            #pragma unroll
            for (int i = 0; i < 4; ++i) {
                bf16x8 a = ld_frag4(&Vs[i * 16 + l16][ks * 32 + quad * 8]);
                acc[i] = __builtin_amdgcn_mfma_f32_16x16x32_bf16(a, bb, acc[i], 0, 0, 0);
            }
        }
    };

    OVStage sA, sB;
    stage_load(sA, (jt0 + 0) * 64);
    stage_load(sB, (jt0 + 1) * 64);

    for (int t = 0; t < jtn; t += 2) {
        lds_write(sA, (jt0 + t) * 64);            // compiler waits sA only
        if (t + 2 < jtn) stage_load(sA, (jt0 + t + 2) * 64);
        lgkm0_bar();
        mfma_tile();
        bar_fenced();
        if (t + 1 < jtn) {
            lds_write(sB, (jt0 + t + 1) * 64);
            if (t + 3 < jtn) stage_load(sB, (jt0 + t + 3) * 64);
            lgkm0_bar();
            mfma_tile();
            bar_fenced();
        }
    }

    // epilogue: d = i*16+quad*4+r, s = s0 + wave*16 + l16 (always < TPAD)
    float* Mp = Mpart + (size_t)(jc * BEH + be) * DE * MPSTRIDE;
    const int s = s0 + wave * 16 + l16;
    #pragma unroll
    for (int i = 0; i < 4; ++i) {
        #pragma unroll
        for (int r = 0; r < 4; ++r) {
            const int d = i * 16 + quad * 4 + r;
            Mp[(size_t)d * MPSTRIDE + s] = acc[i][r];
        }
    }
}

// ---------------------------------------------------------------------------
// Kernel 3 (MFMA): fused attention. v7 — mreduce FUSED into M-staging:
// reads the 4 fp32 Mpart partials directly, sums ((j0+j1)+j2)+j3 and packs
// to bf16 in lds_write — bit-identical to the old mreduce+Mtb path. With the
// be-colocating XCD remap, each XCD's 2 bes x 1.7 MB of Mpart is L2-resident
// after the first it-block, so HBM bytes ~= what mreduce paid; we delete one
// dispatch + the Mtb write/read round-trip. M has a 1-deep register stage
// (16 x float4), issued one compute phase (~500cy) ahead — covers L2 latency.
// ---------------------------------------------------------------------------
struct AStage { uint4 k0, k1, p0, p1; };
struct MStage { float4 a[16]; };   // [jc][quartet], static-indexed only

__global__ __launch_bounds__(256) void attn7_kernel(
    const short* __restrict__ Qb, const short* __restrict__ Kb,
    const float* __restrict__ Mpart, const short* __restrict__ Pbf,
    float* __restrict__ Hbuf)
{
    __shared__ __align__(16) short Qs[64][72];  // [i][d]
    __shared__ __align__(16) short Ks[64][72];  // [s][d]
    __shared__ __align__(16) short Ms[64][72];  // [d][s]
    __shared__ __align__(16) short Ps[64][72];  // [i][s]: punish tile, then Wl

    // XCD-aware bijective remap of (it, be): xcd owns be pair {2x, 2x+1}.
    const int flat = blockIdx.x + TTILES * blockIdx.y;   // 0..415
    const int xcd = flat & 7;
    const int j8  = flat >> 3;        // 0..51
    const int it  = j8 % 26;
    const int be  = xcd * 2 + (j8 / 26);

    const int b = be >> 3, e = be & 7;
    const int i0 = it * 64;
    const short* Qh = Qb + (size_t)be * DE * TT;
    const short* Kh = Kb + (size_t)be * DE * TT;
    const float* Mh = Mpart + (size_t)be * DE * MPSTRIDE;   // jc=0 slice
    const size_t jstride = (size_t)BEH * DE * MPSTRIDE;

    const int tid  = threadIdx.x;
    const int wave = tid >> 6, lane = tid & 63;
    const int quad = lane >> 4, l16 = lane & 15;

    const float invs = 0.024598297f;  // 1/sqrt(1653)

    const int srow = tid >> 2, scg = (tid & 3) * 16;
    const int gi = i0 + srow;
    const bool giv = (gi < TT);
    const int ri = min(gi, TT - 1);

    {   // Q: staged once
        uint4 z = make_uint4(0u, 0u, 0u, 0u);
        uint4 v0 = *(const uint4*)(Qh + (size_t)ri * DE + scg);
        uint4 v1 = *(const uint4*)(Qh + (size_t)ri * DE + scg + 8);
        if (!giv) { v0 = z; v1 = z; }
        *(uint4*)&Qs[srow][scg]     = v0;
        *(uint4*)&Qs[srow][scg + 8] = v1;
    }

    f32x4 out[4];
    #pragma unroll
    for (int i = 0; i < 4; ++i) out[i] = (f32x4){0.f, 0.f, 0.f, 0.f};

    auto stage_kp = [&](AStage& S, int s0) {   // raw clamped loads only
        const int gs = s0 + srow;
        const int rs = min(gs, TT - 1);
        S.k0 = *(const uint4*)(Kh + (size_t)rs * DE + scg);
        S.k1 = *(const uint4*)(Kh + (size_t)rs * DE + scg + 8);
        S.p0 = *(const uint4*)(Pbf + (size_t)ri * TPAD + s0 + scg);
        S.p1 = *(const uint4*)(Pbf + (size_t)ri * TPAD + s0 + scg + 8);
    };

    auto stage_m = [&](MStage& M, int s0) {    // 4 jc partials, fp32
        const float* mp = Mh + (size_t)srow * MPSTRIDE + s0 + scg;
        #pragma unroll
        for (int jc = 0; jc < 4; ++jc) {
            const float* q = mp + jc * jstride;
            M.a[jc * 4 + 0] = *(const float4*)(q);
            M.a[jc * 4 + 1] = *(const float4*)(q + 4);
            M.a[jc * 4 + 2] = *(const float4*)(q + 8);
            M.a[jc * 4 + 3] = *(const float4*)(q + 12);
        }
    };

    auto lds_write = [&](const AStage& S, const MStage& M, int s0) {
        const int gs = s0 + srow;
        const uint4 z = make_uint4(0u, 0u, 0u, 0u);
        const bool kv = (gs < TT);
        uint4 k0 = kv ? S.k0 : z, k1 = kv ? S.k1 : z;
        uint4 p0 = giv ? S.p0 : z, p1 = giv ? S.p1 : z;
        *(uint4*)&Ks[srow][scg]     = k0;
        *(uint4*)&Ks[srow][scg + 8] = k1;
        *(uint4*)&Ps[srow][scg]     = p0;
        *(uint4*)&Ps[srow][scg + 8] = p1;
        // M: sum 4 fp32 partials (left-assoc, == old mreduce) + pack to bf16.
        #pragma unroll
        for (int q = 0; q < 4; ++q) {
            float4 a0 = M.a[q], a1 = M.a[4 + q], a2 = M.a[8 + q], a3 = M.a[12 + q];
            float s0v = a0.x + a1.x + a2.x + a3.x;
            float s1v = a0.y + a1.y + a2.y + a3.y;
            float s2v = a0.z + a1.z + a2.z + a3.z;
            float s3v = a0.w + a1.w + a2.w + a3.w;
            uint2 o; o.x = pack2(s0v, s1v); o.y = pack2(s2v, s3v);
            *(uint2*)&Ms[srow][scg + q * 4] = o;
        }
    };

    auto compute = [&]() {
        f32x4 w[4];
        #pragma unroll
        for (int i = 0; i < 4; ++i) w[i] = (f32x4){0.f, 0.f, 0.f, 0.f};
        #pragma unroll
        for (int ks = 0; ks < 2; ++ks) {
            bf16x8 a = *(const bf16x8*)&Qs[wave * 16 + l16][ks * 32 + quad * 8];
            #pragma unroll
            for (int stile = 0; stile < 4; ++stile) {
                bf16x8 bb = *(const bf16x8*)&Ks[stile * 16 + l16][ks * 32 + quad * 8];
                w[stile] = __builtin_amdgcn_mfma_f32_16x16x32_bf16(a, bb, w[stile], 0, 0, 0);
            }
        }

        // scale by punish, write Wl back into the Ps buffer (wave-private rows)
        #pragma unroll
        for (int stile = 0; stile < 4; ++stile) {
            const int sl = stile * 16 + l16;
            #pragma unroll
            for (int r = 0; r < 4; ++r) {
                const int il = wave * 16 + quad * 4 + r;
                float v = w[stile][r] * invs * bf2f(Ps[il][sl]);
                Ps[il][sl] = f2bf(v);
            }
        }

        #pragma unroll
        for (int ks = 0; ks < 2; ++ks) {
            bf16x8 a = *(const bf16x8*)&Ps[wave * 16 + l16][ks * 32 + quad * 8];
            #pragma unroll
            for (int dt = 0; dt < 4; ++dt) {
                bf16x8 bb = *(const bf16x8*)&Ms[dt * 16 + l16][ks * 32 + quad * 8];
                out[dt] = __builtin_amdgcn_mfma_f32_16x16x32_bf16(a, bb, out[dt], 0, 0, 0);
            }
        }
    };

    AStage sA, sB;
    MStage sM;
    stage_kp(sA, 0);
    stage_kp(sB, 64);
    stage_m(sM, 0);
    lgkm0_bar();   // Qs visible; staged loads stay in flight

    for (int tt = 0; tt < TTILES; tt += 2) {
        lds_write(sA, sM, tt * 64);                   // waits sA + sM
        if (tt + 2 < TTILES) stage_kp(sA, (tt + 2) * 64);
        stage_m(sM, (tt + 1) * 64);                   // next tile's M (L2-hit)
        lgkm0_bar();
        compute();
        bar_fenced();
        lds_write(sB, sM, (tt + 1) * 64);
        if (tt + 3 < TTILES) stage_kp(sB, (tt + 3) * 64);
        if (tt + 2 < TTILES) stage_m(sM, (tt + 2) * 64);
        lgkm0_bar();
        compute();
        bar_fenced();
    }

    #pragma unroll
    for (int dt = 0; dt < 4; ++dt) {
        const int d = dt * 16 + l16;
        #pragma unroll
        for (int r = 0; r < 4; ++r) {
            const int go = i0 + wave * 16 + quad * 4 + r;
            if (go < TT)
                Hbuf[((size_t)b * TT + go) * DD + e * 64 + d] = out[dt][r];
        }
    }
}

// ---------------------------------------------------------------------------
// Kernel 4: final projection (fp32 SGEMM, precision anchor). v3 (unchanged
// R7): double-buffered LDS, ONE barrier per k-step, loads 1 iter ahead.
// ---------------------------------------------------------------------------
__global__ __launch_bounds__(256) void oproj3_kernel(
    const float* __restrict__ H, const float* __restrict__ Wo,
    const float* __restrict__ bo, float* __restrict__ out)
{
    __shared__ float Hs[2][16][68];
    __shared__ float Ns[2][16][68];

    const int tt = blockIdx.x, nt = blockIdx.y, b = blockIdx.z;
    const int t0 = tt * 64, n0 = nt * 64;
    const float* Hb = H + (size_t)b * TT * DD;

    const int tid = threadIdx.x;
    const int tx = tid & 15, ty = tid >> 4;
    const int lrow = tid >> 2, lq = tid & 3;
    const int trow = t0 + lrow;
    const int rx = min(trow, TT - 1);

    float acc[4][4] = {};
    float4 hv, wv;

    auto stage = [&](int k0) {   // raw clamped loads
        hv = *(const float4*)(Hb + (size_t)rx * DD + k0 + lq * 4);
        wv = *(const float4*)(Wo + (size_t)(n0 + lrow) * DD + k0 + lq * 4);
    };
    auto lds_write = [&](int buf) {
        float4 h2 = (trow < TT) ? hv : make_float4(0.f, 0.f, 0.f, 0.f);
        Hs[buf][lq*4+0][lrow] = h2.x; Hs[buf][lq*4+1][lrow] = h2.y;
        Hs[buf][lq*4+2][lrow] = h2.z; Hs[buf][lq*4+3][lrow] = h2.w;
        Ns[buf][lq*4+0][lrow] = wv.x; Ns[buf][lq*4+1][lrow] = wv.y;
        Ns[buf][lq*4+2][lrow] = wv.z; Ns[buf][lq*4+3][lrow] = wv.w;
    };

    stage(0);
    lds_write(0);
    for (int it = 0; it < 32; ++it) {
        lgkm0_bar();                     // buf[it&1] visible to all waves
        if (it + 1 < 32) stage((it + 1) * 16);   // in flight under compute
        const int cur = it & 1;
        #pragma unroll
        for (int k = 0; k < 16; ++k) {
            float4 a4 = *(const float4*)(&Hs[cur][k][ty*4]);
            float4 c4 = *(const float4*)(&Ns[cur][k][tx*4]);
            float a[4] = {a4.x, a4.y, a4.z, a4.w};
            float c[4] = {c4.x, c4.y, c4.z, c4.w};
            #pragma unroll
            for (int i = 0; i < 4; ++i)
                #pragma unroll
                for (int j = 0; j < 4; ++j)
                    acc[i][j] = fmaf(a[i], c[j], acc[i][j]);
        }
        if (it + 1 < 32) lds_write((it + 1) & 1);   // other buffer: no race
    }

    #pragma unroll
    for (int i = 0; i < 4; ++i) {
        const int t = t0 + ty*4 + i;
        if (t < TT) {
            float4 v;
            v.x = acc[i][0] + bo[n0 + tx*4 + 0];
            v.y = acc[i][1] + bo[n0 + tx*4 + 1];
            v.z = acc[i][2] + bo[n0 + tx*4 + 2];
            v.w = acc[i][3] + bo[n0 + tx*4 + 3];
            *(float4*)(out + ((size_t)b * TT + t) * DD + n0 + tx*4) = v;
        }
    }
}

// ---------------------------------------------------------------------------
extern "C" void kernel_launch(void* const* d_in, const int* in_sizes, int n_in,
                              void* d_out, int out_size, void* d_ws, size_t ws_size,
                              hipStream_t stream)
{
    (void)in_sizes; (void)n_in; (void)out_size; (void)ws_size;

    const float* X    = (const float*)d_in[0];
    const float* Wq   = (const float*)d_in[1];
    const float* bq   = (const float*)d_in[2];
    const float* Wk   = (const float*)d_in[3];
    const float* bk   = (const float*)d_in[4];
    const float* Wv   = (const float*)d_in[5];
    const float* bv   = (const float*)d_in[6];
    const float* Wo   = (const float*)d_in[7];
    const float* bo   = (const float*)d_in[8];
    const float* P    = (const float*)d_in[9];
    const float* orth = (const float*)d_in[10];
    float* out = (float*)d_out;

    // Workspace layout (~58 MB). NOTE: Hbuf no longer aliases Mpart —
    // attn7 reads Mpart while writing Hbuf.
    //   Qb/Kb/Vb bf16 [B*D*T]        3 x 3,385,344 B
    //   Pbf      bf16 [T*TPAD]           5,501,184 B
    //   Xb16     bf16 [B*T*D]            3,385,344 B
    //   Wqb/Wkb/Wvb bf16 [D*D]       3 x   524,288 B
    //   Mpart    fp32 [4][BE*64][TPAD]  27,262,976 B
    //   Hbuf     fp32 [B*T*D]            6,770,688 B
    char* ws = (char*)d_ws;
    const size_t SZH = (size_t)BB * DD * TT * sizeof(short);
    const size_t SZP = (size_t)TT * TPAD * sizeof(short);
    const size_t SZW = (size_t)DD * DD * sizeof(short);
    const size_t SZM = (size_t)NJC * BEH * DE * MPSTRIDE * sizeof(float);
    short* Qb   = (short*)(ws);
    short* Kb   = (short*)(ws + SZH);
    short* Vb   = (short*)(ws + 2 * SZH);
    short* Pbf  = (short*)(ws + 3 * SZH);
    short* Xb16 = (short*)(ws + 3 * SZH + SZP);
    short* Wqb  = (short*)(ws + 4 * SZH + SZP);
    short* Wkb  = (short*)(ws + 4 * SZH + SZP + SZW);
    short* Wvb  = (short*)(ws + 4 * SZH + SZP + 2 * SZW);
    float* Mpart = (float*)(ws + 4 * SZH + SZP + 3 * SZW);
    float* Hbuf  = (float*)(ws + 4 * SZH + SZP + 3 * SZW + SZM);

    dim3 blk(256);

    prep_kernel<<<dim3(1024), blk, 0, stream>>>(X, Wq, Wk, Wv, P,
                                                Xb16, Wqb, Wkb, Wvb, Pbf);

    dim3 g1(TTILES, DD / 64, BB * 3);
    proj7_kernel<<<g1, blk, 0, stream>>>(Xb16, Wqb, bq, Wkb, bk, Wvb, bv,
                                         Qb, Kb, Vb);

    dim3 g2(SQN, BEH, NJC);
    ovt8_kernel<<<g2, blk, 0, stream>>>(orth, Vb, Mpart);

    dim3 g3(TTILES, BEH);
    attn7_kernel<<<g3, blk, 0, stream>>>(Qb, Kb, Mpart, Pbf, Hbuf);

    dim3 g4(TTILES, DD / 64, BB);
    oproj3_kernel<<<g4, blk, 0, stream>>>(Hbuf, Wo, bo, out);
}